// Round 3
// baseline (659.820 us; speedup 1.0000x reference)
//
#include <hip/hip_runtime.h>

// Problem dims (LRNetLinear): out = B x O, x = B x I, weights O x I
#define I_DIM 4096
#define O_DIM 4096
#define B_DIM 4096

typedef __bf16 bf16;
typedef __attribute__((ext_vector_type(8))) __bf16 bf16x8;
typedef __attribute__((ext_vector_type(4))) float f32x4;
typedef __attribute__((ext_vector_type(8))) unsigned short ushort8;

// fp32 -> bf16 bits, round-to-nearest-even
__device__ inline unsigned short f2bf_bits(float f) {
    unsigned u = __builtin_bit_cast(unsigned, f);
    unsigned r = 0x7fffu + ((u >> 16) & 1u);
    return (unsigned short)((u + r) >> 16);
}

__device__ inline void lr_wmv(float tn, float tp, float s,
                              unsigned short& wm, unsigned short& wv) {
    float m = fmaxf(fmaxf(tn, tp), 0.0f);
    float en = __expf(tn - m);
    float ez = __expf(-m);
    float ep = __expf(tp - m);
    float inv = __builtin_amdgcn_rcpf(en + ez + ep);
    float pn = en * inv, pp = ep * inv;
    float d = pp - pn;
    wm = f2bf_bits(d * s);
    wv = f2bf_bits((pp + pn - d * d) * (s * s));
}

// ---------------------------------------------------------------------------
// Fused prep: blocks [0, nbx): x -> bf16(x), bf16(x^2)   (8 elems/thr)
//             blocks [nbx,..): weights -> bf16 w_mean, w_var (4 elems/thr)
// ---------------------------------------------------------------------------
__global__ void prep_all(const float4* __restrict__ x,
                         ushort8* __restrict__ xb8, ushort8* __restrict__ x2b8,
                         const float4* __restrict__ tn, const float4* __restrict__ tp,
                         const float4* __restrict__ sc,
                         ushort4* __restrict__ wm, ushort4* __restrict__ wv,
                         int nbx) {
    const int bid = blockIdx.x;
    if (bid < nbx) {
        size_t i = (size_t)bid * blockDim.x + threadIdx.x;
        float4 a = x[2 * i];
        float4 b = x[2 * i + 1];
        ushort8 o1, o2;
        o1[0] = f2bf_bits(a.x); o1[1] = f2bf_bits(a.y);
        o1[2] = f2bf_bits(a.z); o1[3] = f2bf_bits(a.w);
        o1[4] = f2bf_bits(b.x); o1[5] = f2bf_bits(b.y);
        o1[6] = f2bf_bits(b.z); o1[7] = f2bf_bits(b.w);
        o2[0] = f2bf_bits(a.x * a.x); o2[1] = f2bf_bits(a.y * a.y);
        o2[2] = f2bf_bits(a.z * a.z); o2[3] = f2bf_bits(a.w * a.w);
        o2[4] = f2bf_bits(b.x * b.x); o2[5] = f2bf_bits(b.y * b.y);
        o2[6] = f2bf_bits(b.z * b.z); o2[7] = f2bf_bits(b.w * b.w);
        xb8[i] = o1;
        x2b8[i] = o2;
    } else {
        size_t i = (size_t)(bid - nbx) * blockDim.x + threadIdx.x;
        float4 a = tn[i];
        float4 b = tp[i];
        float4 s = sc[i];
        ushort4 om, ov;
        lr_wmv(a.x, b.x, s.x, om.x, ov.x);
        lr_wmv(a.y, b.y, s.y, om.y, ov.y);
        lr_wmv(a.z, b.z, s.z, om.z, ov.z);
        lr_wmv(a.w, b.w, s.w, om.w, ov.w);
        wm[i] = om;
        wv[i] = ov;
    }
}

// ---------------------------------------------------------------------------
// Fused dual GEMM with WAVE SPECIALIZATION:
//   block = 4 waves, tile BM=128 x BN=64, BK=64, XOR-swizzled LDS (16B
//   granule (row,cg) stored at cg ^ (row&7) — measured 0 bank conflicts).
//   waves 0,1: mu GEMM  (A = bf16(x),  B = w_mean), 64x64 sub-tile each
//   waves 2,3: var GEMM (A = bf16(x^2),B = w_var ), 64x64 sub-tile each
// Each wave: 64 acc regs (4x4 of 16x16x32 MFMA) -> 3 waves/SIMD occupancy.
// Epilogue: var waves dump acc to LDS; mu waves combine with eps -> out.
// ---------------------------------------------------------------------------
#define BM 128
#define BN 64
#define BK 64

__device__ inline void gl_lds16(const bf16* g, bf16* l) {
    __builtin_amdgcn_global_load_lds(
        (const __attribute__((address_space(1))) unsigned int*)g,
        (__attribute__((address_space(3))) unsigned int*)l,
        16, 0, 0);
}

__global__ __launch_bounds__(256, 3)
void fused_dual_gemm(const bf16* __restrict__ Xb, const bf16* __restrict__ X2b,
                     const bf16* __restrict__ Wm, const bf16* __restrict__ Wv,
                     const float* __restrict__ eps, float* __restrict__ out) {
    __shared__ char smem[49152];               // 48 KB
    bf16* sX  = (bf16*)(smem);                 // 16 KB  128x64
    bf16* sX2 = (bf16*)(smem + 16384);         // 16 KB  128x64
    bf16* sWm = (bf16*)(smem + 32768);         //  8 KB   64x64
    bf16* sWv = (bf16*)(smem + 40960);         //  8 KB   64x64

    const int tid  = threadIdx.x;
    const int lane = tid & 63;
    const int wave = tid >> 6;

    const int bm = blockIdx.y * BM;
    const int bn = blockIdx.x * BN;

    // ---- staging: chunk = 1 KB (64 lanes x 16 B) covering 8 rows of 64.
    // lane -> rowoff = lane>>3, stored granule lane&7, logical cg = (lane&7)^rowoff
    const int rowoff = lane >> 3;
    const int cgoff  = ((lane & 7) ^ rowoff) << 3;   // elems within row

    // 12 staging jobs per wave: sX c={w,w+4,w+8,w+12}, sX2 same, sWm c={w,w+4}, sWv same
    const bf16* gX[4]; const bf16* gX2[4]; int loffX[4];
    const bf16* gWm[2]; const bf16* gWv[2]; int loffW[2];
#pragma unroll
    for (int j = 0; j < 4; ++j) {
        const int c = wave + 4 * j;
        const size_t ra = (size_t)(bm + c * 8 + rowoff) * I_DIM + cgoff;
        gX[j]  = Xb  + ra;
        gX2[j] = X2b + ra;
        loffX[j] = c << 9;
    }
#pragma unroll
    for (int j = 0; j < 2; ++j) {
        const int c = wave + 4 * j;
        const size_t rb = (size_t)(bn + c * 8 + rowoff) * I_DIM + cgoff;
        gWm[j] = Wm + rb;
        gWv[j] = Wv + rb;
        loffW[j] = c << 9;
    }

    // ---- wave specialization
    const bf16* myA = (wave >= 2) ? sX2 : sX;
    const bf16* myB = (wave >= 2) ? sWv : sWm;
    const int m0 = (wave & 1) << 6;            // 0 or 64

    // ---- fragment offsets (16x16x32: row = lane&15, k = (lane>>4)*8)
    const int fr  = lane & 15;
    const int sw0 = (((lane >> 4) ^ (fr & 7)) << 3);

    f32x4 acc[4][4];
    const f32x4 z = {0.0f, 0.0f, 0.0f, 0.0f};
#pragma unroll
    for (int mi = 0; mi < 4; ++mi)
#pragma unroll
        for (int ni = 0; ni < 4; ++ni) acc[mi][ni] = z;

    for (int k0 = 0; k0 < I_DIM; k0 += BK) {
        __syncthreads();   // previous iteration's reads done before overwrite
#pragma unroll
        for (int j = 0; j < 4; ++j) {
            gl_lds16(gX[j]  + k0, sX  + loffX[j]);
            gl_lds16(gX2[j] + k0, sX2 + loffX[j]);
        }
#pragma unroll
        for (int j = 0; j < 2; ++j) {
            gl_lds16(gWm[j] + k0, sWm + loffW[j]);
            gl_lds16(gWv[j] + k0, sWv + loffW[j]);
        }
        __syncthreads();   // staging complete (compiler drains vmcnt)

#pragma unroll
        for (int kh = 0; kh < 2; ++kh) {
            const int sw = sw0 ^ (kh << 5);
            bf16x8 a[4];
#pragma unroll
            for (int mi = 0; mi < 4; ++mi)
                a[mi] = *(const bf16x8*)&myA[(m0 + mi * 16 + fr) * BK + sw];
#pragma unroll
            for (int ni = 0; ni < 4; ++ni) {
                bf16x8 b = *(const bf16x8*)&myB[(ni * 16 + fr) * BK + sw];
#pragma unroll
                for (int mi = 0; mi < 4; ++mi)
                    acc[mi][ni] = __builtin_amdgcn_mfma_f32_16x16x32_bf16(
                        a[mi], b, acc[mi][ni], 0, 0, 0);
            }
        }
    }

    // ---- epilogue: C/D layout col = lane&15, row = (lane>>4)*4 + r
    __syncthreads();                            // all K-loop LDS reads done
    float* xfer = (float*)smem;                 // 32 KB: region per var-wave
    if (wave >= 2) {
        float* dst = xfer + ((wave - 2) << 12); // 4096 floats each
#pragma unroll
        for (int mi = 0; mi < 4; ++mi)
#pragma unroll
            for (int ni = 0; ni < 4; ++ni)
#pragma unroll
                for (int r = 0; r < 4; ++r)
                    dst[mi * 1024 + ni * 256 + r * 64 + lane] = acc[mi][ni][r];
    }
    __syncthreads();
    if (wave < 2) {
        const float* src = xfer + (wave << 12);
        const int oc  = lane & 15;
        const int orb = (lane >> 4) << 2;
#pragma unroll
        for (int mi = 0; mi < 4; ++mi) {
#pragma unroll
            for (int ni = 0; ni < 4; ++ni) {
                const int gn = bn + ni * 16 + oc;
                const int gm = bm + m0 + mi * 16 + orb;
#pragma unroll
                for (int r = 0; r < 4; ++r) {
                    const float vv = src[mi * 1024 + ni * 256 + r * 64 + lane];
                    const size_t off = (size_t)(gm + r) * O_DIM + gn;
                    out[off] = fmaf(sqrtf(fmaxf(vv, 1e-8f)), eps[off], acc[mi][ni][r]);
                }
            }
        }
    }
}

// ---------------------------------------------------------------------------
extern "C" void kernel_launch(void* const* d_in, const int* in_sizes, int n_in,
                              void* d_out, int out_size, void* d_ws, size_t ws_size,
                              hipStream_t stream) {
    const float* x   = (const float*)d_in[0];
    const float* tn  = (const float*)d_in[1];
    const float* tp  = (const float*)d_in[2];
    const float* sc  = (const float*)d_in[3];
    const float* eps = (const float*)d_in[4];
    float* out = (float*)d_out;

    const size_t NE = (size_t)O_DIM * I_DIM;   // 16.7M
    unsigned short* xb  = (unsigned short*)d_ws;
    unsigned short* x2b = xb + NE;
    unsigned short* wm  = x2b + NE;
    unsigned short* wv  = wm + NE;

    const int nbx = (int)(NE / 8 / 256);       // 8192  (x path)
    const int nbw = (int)(NE / 4 / 256);       // 16384 (weight path)
    prep_all<<<nbx + nbw, 256, 0, stream>>>(
        (const float4*)x, (ushort8*)xb, (ushort8*)x2b,
        (const float4*)tn, (const float4*)tp, (const float4*)sc,
        (ushort4*)wm, (ushort4*)wv, nbx);

    dim3 grid(O_DIM / BN, B_DIM / BM);   // (64, 32)
    fused_dual_gemm<<<grid, 256, 0, stream>>>(
        (const bf16*)xb, (const bf16*)x2b, (const bf16*)wm, (const bf16*)wv, eps, out);
}

// Round 5
// 551.153 us; speedup vs baseline: 1.1972x; 1.1972x over previous
//
#include <hip/hip_runtime.h>

// Problem dims (LRNetLinear): out = B x O, x = B x I, weights O x I
#define I_DIM 4096
#define O_DIM 4096
#define B_DIM 4096

typedef _Float16 f16;
typedef __attribute__((ext_vector_type(8))) _Float16 f16x8;
typedef __attribute__((ext_vector_type(4))) float f32x4;

struct f16pair { f16 m, v; };

// ---------------------------------------------------------------------------
// Weight transform: 3-way softmax stats -> (w_mean, w_var) in fp16
// ---------------------------------------------------------------------------
__device__ inline f16pair lr_wmv(float tn, float tp, float s) {
    float m = fmaxf(fmaxf(tn, tp), 0.0f);
    float en = __expf(tn - m);
    float ez = __expf(-m);
    float ep = __expf(tp - m);
    float inv = __builtin_amdgcn_rcpf(en + ez + ep);
    float pn = en * inv, pp = ep * inv;
    float d = pp - pn;
    f16pair r;
    r.m = (f16)(d * s);
    r.v = (f16)((pp + pn - d * d) * (s * s));
    return r;
}

// ---------------------------------------------------------------------------
// Fused prep (8 elems/thread both paths):
//   blocks [0, nbx):  x -> f16(x)            (x^2 is formed in-register in GEMM)
//   blocks [nbx, ..): thetas/scales -> f16 w_mean, w_var
// ---------------------------------------------------------------------------
__global__ void prep_all(const float4* __restrict__ x, f16x8* __restrict__ xb8,
                         const float4* __restrict__ tn4, const float4* __restrict__ tp4,
                         const float4* __restrict__ sc4,
                         f16x8* __restrict__ wm8, f16x8* __restrict__ wv8,
                         int nbx) {
    const int bid = blockIdx.x;
    if (bid < nbx) {
        size_t i = (size_t)bid * blockDim.x + threadIdx.x;
        float4 a = x[2 * i];
        float4 b = x[2 * i + 1];
        f16x8 o;
        o[0] = (f16)a.x; o[1] = (f16)a.y; o[2] = (f16)a.z; o[3] = (f16)a.w;
        o[4] = (f16)b.x; o[5] = (f16)b.y; o[6] = (f16)b.z; o[7] = (f16)b.w;
        xb8[i] = o;
    } else {
        size_t i = (size_t)(bid - nbx) * blockDim.x + threadIdx.x;
        float4 a0 = tn4[2 * i], a1 = tn4[2 * i + 1];
        float4 b0 = tp4[2 * i], b1 = tp4[2 * i + 1];
        float4 s0 = sc4[2 * i], s1 = sc4[2 * i + 1];
        f16x8 om, ov;
        f16pair p;
        p = lr_wmv(a0.x, b0.x, s0.x); om[0] = p.m; ov[0] = p.v;
        p = lr_wmv(a0.y, b0.y, s0.y); om[1] = p.m; ov[1] = p.v;
        p = lr_wmv(a0.z, b0.z, s0.z); om[2] = p.m; ov[2] = p.v;
        p = lr_wmv(a0.w, b0.w, s0.w); om[3] = p.m; ov[3] = p.v;
        p = lr_wmv(a1.x, b1.x, s1.x); om[4] = p.m; ov[4] = p.v;
        p = lr_wmv(a1.y, b1.y, s1.y); om[5] = p.m; ov[5] = p.v;
        p = lr_wmv(a1.z, b1.z, s1.z); om[6] = p.m; ov[6] = p.v;
        p = lr_wmv(a1.w, b1.w, s1.w); om[7] = p.m; ov[7] = p.v;
        wm8[i] = om;
        wv8[i] = ov;
    }
}

// ---------------------------------------------------------------------------
// Fused dual GEMM, fp16, register-squared A:
//   128x128 tile, BK=64, 4 waves each 64x64 with DUAL 4x4 accumulators.
//   LDS stages only 3 arrays (X, Wm, Wv) = 48 KB, XOR-swizzled (16B granule
//   (row,cg) stored at cg ^ (row&7) — measured 0 bank conflicts).
//   Per kh: read 4 A + 4 Bm + 4 Bv frags (12 b128) for 32 MFMA = 43.7 FLOP/B;
//   A^2 fragment computed in-register via packed f16 multiply.
// ---------------------------------------------------------------------------
#define BM 128
#define BN 128
#define BK 64

__device__ inline void gl_lds16(const f16* g, f16* l) {
    __builtin_amdgcn_global_load_lds(
        (const __attribute__((address_space(1))) unsigned int*)g,
        (__attribute__((address_space(3))) unsigned int*)l,
        16, 0, 0);
}

__global__ __launch_bounds__(256, 2)
void fused_dual_gemm(const f16* __restrict__ Xb,
                     const f16* __restrict__ Wm, const f16* __restrict__ Wv,
                     const float* __restrict__ eps, float* __restrict__ out) {
    __shared__ f16 smem[24576];                // 48 KB
    f16* sX  = smem;                           // 16 KB  128x64

    const int tid  = threadIdx.x;
    const int lane = tid & 63;
    const int wave = tid >> 6;

    const int bm = blockIdx.y * BM;
    const int bn = blockIdx.x * BN;

    // ---- staging: 48 chunks of 1 KB (64 lanes x 16 B), 12 jobs per wave.
    // chunk cj = wave + 4*j; array = cj>>4 (0=X,1=Wm,2=Wv), local chunk cj&15.
    // lane -> rowoff = lane>>3, stored granule lane&7, logical cg = (lane&7)^rowoff
    const int rowoff = lane >> 3;
    const int cgoff  = ((lane & 7) ^ rowoff) << 3;   // elems within row

    const f16* g[12];
    int loff[12];
#pragma unroll
    for (int j = 0; j < 12; ++j) {
        const int cj  = wave + 4 * j;
        const int arr = cj >> 4;
        const int lc  = cj & 15;
        const int tb  = (arr == 0) ? bm : bn;
        const f16* base = (arr == 0) ? Xb : ((arr == 1) ? Wm : Wv);
        g[j] = base + (size_t)(tb + lc * 8 + rowoff) * I_DIM + cgoff;
        loff[j] = cj << 9;
    }

    // ---- fragment offsets (16x16x32: row = lane&15, k = (lane>>4)*8)
    const int fr  = lane & 15;
    const int sw0 = (((lane >> 4) ^ (fr & 7)) << 3);
    const int m0 = (wave >> 1) << 6;
    const int n0 = (wave & 1) << 6;

    f32x4 accM[4][4];
    f32x4 accV[4][4];
    const f32x4 z = {0.0f, 0.0f, 0.0f, 0.0f};
#pragma unroll
    for (int mi = 0; mi < 4; ++mi)
#pragma unroll
        for (int ni = 0; ni < 4; ++ni) { accM[mi][ni] = z; accV[mi][ni] = z; }

    const f16* sWm = smem + 8192;              // 16 KB  128x64
    const f16* sWv = smem + 16384;             // 16 KB  128x64

    for (int k0 = 0; k0 < I_DIM; k0 += BK) {
        __syncthreads();   // previous iteration's reads done before overwrite
#pragma unroll
        for (int j = 0; j < 12; ++j)
            gl_lds16(g[j] + k0, smem + loff[j]);
        __syncthreads();   // staging complete (compiler drains vmcnt)

#pragma unroll
        for (int kh = 0; kh < 2; ++kh) {
            const int sw = sw0 ^ (kh << 5);
            f16x8 a[4], a2[4];
#pragma unroll
            for (int mi = 0; mi < 4; ++mi) {
                a[mi]  = *(const f16x8*)&sX[(m0 + mi * 16 + fr) * BK + sw];
                a2[mi] = a[mi] * a[mi];        // v_pk_mul_f16 x4 — replaces LDS reads
            }
#pragma unroll
            for (int ni = 0; ni < 4; ++ni) {
                const int rowb = (n0 + ni * 16 + fr) * BK + sw;
                f16x8 bm_ = *(const f16x8*)&sWm[rowb];
                f16x8 bv_ = *(const f16x8*)&sWv[rowb];
#pragma unroll
                for (int mi = 0; mi < 4; ++mi) {
                    accM[mi][ni] = __builtin_amdgcn_mfma_f32_16x16x32_f16(
                        a[mi], bm_, accM[mi][ni], 0, 0, 0);
                    accV[mi][ni] = __builtin_amdgcn_mfma_f32_16x16x32_f16(
                        a2[mi], bv_, accV[mi][ni], 0, 0, 0);
                }
            }
        }
    }

    // ---- epilogue (register-resident): C/D layout col = lane&15, row = (lane>>4)*4 + r
    const int oc  = lane & 15;
    const int orb = (lane >> 4) << 2;
#pragma unroll
    for (int mi = 0; mi < 4; ++mi) {
#pragma unroll
        for (int ni = 0; ni < 4; ++ni) {
            const int gn = bn + n0 + ni * 16 + oc;
            const int gm = bm + m0 + mi * 16 + orb;
#pragma unroll
            for (int r = 0; r < 4; ++r) {
                const size_t off = (size_t)(gm + r) * O_DIM + gn;
                const float mu = accM[mi][ni][r];
                const float vv = accV[mi][ni][r];
                out[off] = fmaf(sqrtf(fmaxf(vv, 1e-8f)), eps[off], mu);
            }
        }
    }
}

// ---------------------------------------------------------------------------
extern "C" void kernel_launch(void* const* d_in, const int* in_sizes, int n_in,
                              void* d_out, int out_size, void* d_ws, size_t ws_size,
                              hipStream_t stream) {
    const float* x   = (const float*)d_in[0];
    const float* tn  = (const float*)d_in[1];
    const float* tp  = (const float*)d_in[2];
    const float* sc  = (const float*)d_in[3];
    const float* eps = (const float*)d_in[4];
    float* out = (float*)d_out;

    const size_t NE = (size_t)O_DIM * I_DIM;   // 16.7M
    f16* xb = (f16*)d_ws;                      // 32 MB
    f16* wm = xb + NE;                         // 32 MB
    f16* wv = wm + NE;                         // 32 MB

    const int nbx = (int)(NE / 8 / 256);       // 8192 (x path)
    const int nbw = (int)(NE / 8 / 256);       // 8192 (weight path)
    prep_all<<<nbx + nbw, 256, 0, stream>>>(
        (const float4*)x, (f16x8*)xb,
        (const float4*)tn, (const float4*)tp, (const float4*)sc,
        (f16x8*)wm, (f16x8*)wv, nbx);

    dim3 grid(O_DIM / BN, B_DIM / BM);   // (32, 32)
    fused_dual_gemm<<<grid, 256, 0, stream>>>(
        (const f16*)xb, (const f16*)wm, (const f16*)wv, eps, out);
}